// Round 2
// baseline (826.406 us; speedup 1.0000x reference)
//
#include <hip/hip_runtime.h>
#include <stdint.h>
#include <math.h>

typedef unsigned short u16;
typedef short bf16x8 __attribute__((ext_vector_type(8)));
typedef float f32x4 __attribute__((ext_vector_type(4)));

#define MFMA16x16x32(a,b,c) __builtin_amdgcn_mfma_f32_16x16x32_bf16((a),(b),(c),0,0,0)

typedef __attribute__((address_space(3))) void as3_void;
typedef const __attribute__((address_space(1))) void as1_void;

__device__ __forceinline__ void g2l16(const void* g, void* l){
#if __has_builtin(__builtin_amdgcn_global_load_lds)
  __builtin_amdgcn_global_load_lds((as1_void*)g, (as3_void*)l, 16, 0, 0);
#else
  *(int4*)l = *(const int4*)g;
#endif
}

__device__ __forceinline__ u16 f2bf(float f){
  uint32_t u = __builtin_bit_cast(uint32_t, f);
  u += 0x7fffu + ((u >> 16) & 1u);
  return (u16)(u >> 16);
}
__device__ __forceinline__ float bf2f(u16 h){
  uint32_t u = ((uint32_t)h) << 16;
  return __builtin_bit_cast(float, u);
}
__device__ __forceinline__ void unpack8(int4 v, float* o){
  uint32_t w0=(uint32_t)v.x, w1=(uint32_t)v.y, w2=(uint32_t)v.z, w3=(uint32_t)v.w;
  o[0]=__builtin_bit_cast(float, w0<<16); o[1]=__builtin_bit_cast(float, w0&0xffff0000u);
  o[2]=__builtin_bit_cast(float, w1<<16); o[3]=__builtin_bit_cast(float, w1&0xffff0000u);
  o[4]=__builtin_bit_cast(float, w2<<16); o[5]=__builtin_bit_cast(float, w2&0xffff0000u);
  o[6]=__builtin_bit_cast(float, w3<<16); o[7]=__builtin_bit_cast(float, w3&0xffff0000u);
}
__device__ __forceinline__ int iclampi(int v,int lo,int hi){ return v<lo?lo:(v>hi?hi:v); }

// ---------------------------------------------------------------------------
// repack weights to bf16 [N][K] (k contiguous per out-channel), K tap-major.
__global__ void k_repack(const float* __restrict__ w_reset, const float* __restrict__ b_reset,
                         const float* __restrict__ w_update, const float* __restrict__ b_update,
                         const float* __restrict__ w_out, const float* __restrict__ w_offset,
                         const float* __restrict__ w_align,
                         u16* __restrict__ wgate, u16* __restrict__ wout,
                         u16* __restrict__ walign, float* __restrict__ woff,
                         float* __restrict__ biascat){
  int idx = blockIdx.x * 256 + threadIdx.x;
  if (idx < 512*4608){
    int n = idx / 4608, k = idx % 4608;
    int tap = k >> 9, c = k & 511;
    int ky = tap/3, kx = tap%3;
    float v = (n < 256) ? w_update[((n*512 + c)*3 + ky)*3 + kx]
                        : w_reset[(((n-256)*512 + c)*3 + ky)*3 + kx];
    wgate[idx] = f2bf(v);
  }
  if (idx < 256*4608){
    int n = idx / 4608, k = idx % 4608;
    int tap = k >> 9, c = k & 511;
    int ky = tap/3, kx = tap%3;
    wout[idx] = f2bf(w_out[((n*512 + c)*3 + ky)*3 + kx]);
  }
  if (idx < 256*2304){
    int n = idx / 2304, k = idx % 2304;
    int tap = k >> 8, c = k & 255;
    int ky = tap/3, kx = tap%3;
    walign[idx] = f2bf(w_align[((n*256 + c)*3 + ky)*3 + kx]);
  }
  if (idx < 1458) woff[idx] = w_offset[idx] * (1.f/256.f);
  if (idx < 512) biascat[idx] = (idx < 256) ? b_update[idx] : b_reset[idx-256];
}

// ---------------------------------------------------------------------------
// Zero only the padding ring of an NHWC-padded buffer (interior gets fully
// overwritten by producers). buf: [8][H][H][C] u16, pad width P.
__global__ void k_ring(u16* __restrict__ buf, int H, int P, int C){
  int idx = blockIdx.x*256 + threadIdx.x;
  int cpx = C >> 3;
  int inner = H - 2*P;
  int ringpb = H*H - inner*inner;
  int total = 8 * ringpb * cpx;
  if (idx >= total) return;
  int px = idx / cpx, ch = (idx - px*cpx) * 8;
  int b = px / ringpb, p = px - b*ringpb;
  int PH = P*H;
  int row, col;
  if (p < PH){ row = p / H; col = p - row*H; }
  else if (p < 2*PH){ int q = p - PH; int r2 = q / H; row = H - P + r2; col = q - r2*H; }
  else { int q = p - 2*PH; int r2 = q / (2*P); row = P + r2; int c2 = q - r2*2*P;
         col = (c2 < P) ? c2 : inner + c2; }
  int4 z = {0,0,0,0};
  *(int4*)(buf + (((b*H + row)*H) + col)*C + ch) = z;
}

// ---------------------------------------------------------------------------
// NCHW fp32 -> NHWC bf16: inputs -> stacked[...,0:256] & stacked2[...,0:256]
// (pad=1 layout 66x66), in_state -> x2pad (pad=4 layout 72x72). One row/block.
__global__ __launch_bounds__(256) void k_transform(const float* __restrict__ inputs,
    const float* __restrict__ in_state, u16* __restrict__ stacked,
    u16* __restrict__ stacked2, u16* __restrict__ x2pad){
  __shared__ u16 t1[64*264];
  __shared__ u16 t2[64*264];
  int tid = threadIdx.x, bh = blockIdx.x;
  int b = bh >> 6, h = bh & 63;
  int w = tid & 63, cq = tid >> 6;
  for (int i = 0; i < 64; ++i){
    int c = i*4 + cq;
    int gi = ((b*256 + c)*64 + h)*64 + w;
    t1[w*264 + c] = f2bf(inputs[gi]);
    t2[w*264 + c] = f2bf(in_state[gi]);
  }
  __syncthreads();
  int px = tid >> 2, cg = tid & 3;
#pragma unroll
  for (int u = 0; u < 8; ++u){
    int c = cg*64 + u*8;
    int4 v1 = *(const int4*)(t1 + px*264 + c);
    int4 v2 = *(const int4*)(t2 + px*264 + c);
    *(int4*)(stacked  + (((b*66 + h+1)*66) + (px+1))*512 + c) = v1;
    *(int4*)(stacked2 + (((b*66 + h+1)*66) + (px+1))*512 + c) = v1;
    *(int4*)(x2pad    + (((b*72 + h+4)*72) + (px+4))*256 + c) = v2;
  }
}

// ---------------------------------------------------------------------------
// Correlation as masked local GEMM: 8x8 x1-tile vs 16x16 x2-halo, K=256.
__global__ __launch_bounds__(256) void k_corr(const u16* __restrict__ stacked,
    const u16* __restrict__ x2pad, float* __restrict__ corr){
  __shared__ u16 lA[8192];   // 64px x 128ch, frag-ordered
  __shared__ u16 lB[32768];  // 256px x 128ch, frag-ordered
  int tid = threadIdx.x, idx = blockIdx.x;
  int b = idx >> 6, ty = (idx >> 3) & 7, tx = idx & 7;
  int h0 = ty*8, w0 = tx*8;
  int wave = tid >> 6, lane = tid & 63, l15 = lane & 15, quad = lane >> 4;
  f32x4 acc[4][4];
#pragma unroll
  for (int i=0;i<4;i++)
#pragma unroll
    for (int j=0;j<4;j++){ f32x4 z = {0.f,0.f,0.f,0.f}; acc[i][j] = z; }

  for (int s = 0; s < 2; ++s){
#pragma unroll
    for (int i = 0; i < 4; ++i){
      int j = tid + i*256;
      int ml = j & 15, q = (j>>4)&3, mt = (j>>6)&3, ks = j >> 8;
      int px = mt*16 + ml, py = px >> 3, pxx = px & 7;
      const u16* g = stacked + (((b*66 + h0+py+1)*66) + (w0+pxx+1))*512 + s*128 + ks*32 + q*8;
      g2l16(g, lA + j*8);
    }
#pragma unroll
    for (int i = 0; i < 16; ++i){
      int j = tid + i*256;
      int nl = j & 15, q = (j>>4)&3, nt = (j>>6)&15, ks = j >> 10;
      int qp = nt*16 + nl, qy = qp >> 4, qx = qp & 15;
      const u16* g = x2pad + (((b*72 + h0+qy)*72) + (w0+qx))*256 + s*128 + ks*32 + q*8;
      g2l16(g, lB + j*8);
    }
    __syncthreads();
#pragma unroll
    for (int ks = 0; ks < 4; ++ks){
      bf16x8 bv[4];
#pragma unroll
      for (int ni=0; ni<4; ++ni){
        int nt = wave*4 + ni;
        bv[ni] = *(const bf16x8*)(lB + (((ks*16 + nt)*4 + quad)*16 + l15)*8);
      }
#pragma unroll
      for (int mi=0; mi<4; ++mi){
        bf16x8 av = *(const bf16x8*)(lA + (((ks*4 + mi)*4 + quad)*16 + l15)*8);
#pragma unroll
        for (int ni=0; ni<4; ++ni) acc[mi][ni] = MFMA16x16x32(av, bv[ni], acc[mi][ni]);
      }
    }
    __syncthreads();
  }
#pragma unroll
  for (int mi=0; mi<4; ++mi){
#pragma unroll
    for (int ni=0; ni<4; ++ni){
      int n = wave*64 + ni*16 + l15;
      int qy = n >> 4, qx = n & 15;
#pragma unroll
      for (int r=0; r<4; ++r){
        int m = mi*16 + quad*4 + r;
        int py = m >> 3, pxx = m & 7;
        int dy = qy - py, dx = qx - pxx;
        if ((unsigned)dy <= 8u && (unsigned)dx <= 8u)
          corr[(((b*64 + h0+py)*64) + (w0+pxx))*81 + dy*9 + dx] = acc[mi][ni][r];
      }
    }
  }
}

// ---------------------------------------------------------------------------
// offsets = corr @ woff^T per pixel. One half-row (32 px) per block.
__global__ __launch_bounds__(256) void k_offset(const float* __restrict__ corr,
    const float* __restrict__ woff, float* __restrict__ offs){
  __shared__ float lc[32*84];
  __shared__ float lw[18*84];
  int tid = threadIdx.x, blk = blockIdx.x;
  int row = blk >> 1, half = blk & 1;
  int base = row*5184 + half*32*81;
  for (int i = tid; i < 32*81; i += 256){
    int px = i / 81, d = i % 81;
    lc[px*84 + d] = corr[base + i];
  }
  for (int i = tid; i < 18*84; i += 256){
    int o = i / 84, d = i % 84;
    if (d < 81) lw[i] = woff[o*81 + d];
  }
  __syncthreads();
  int px = tid & 31, og = tid >> 5;
  for (int o = og; o < 18; o += 8){
    float s = 0.f;
#pragma unroll
    for (int dd = 0; dd < 20; ++dd){
      float4 a = *(const float4*)(lc + px*84 + dd*4);
      float4 wv = *(const float4*)(lw + o*84 + dd*4);
      s += a.x*wv.x + a.y*wv.y + a.z*wv.z + a.w*wv.w;
    }
    s += lc[px*84 + 80] * lw[o*84 + 80];
    offs[(row*64 + half*32 + px)*18 + o] = s;
  }
}

// ---------------------------------------------------------------------------
// Deformable conv: per tap, bilinear-sampled A-tile (64px x 256ch) in LDS,
// MFMA against walign. Writes aligned into stacked[...,256:512].
__global__ __launch_bounds__(256) void k_deform(const u16* __restrict__ x2pad,
    const float* __restrict__ offs, const u16* __restrict__ walign,
    u16* __restrict__ stacked){
  __shared__ u16 lA[16384];
  int tid = threadIdx.x, bh = blockIdx.x;
  int b = bh >> 6, h = bh & 63;
  int wave = tid >> 6, lane = tid & 63, l15 = lane & 15, quad = lane >> 4;
  int px = tid >> 2, cg = tid & 3;
  int mt_s = px >> 4, ml_s = px & 15;
  f32x4 acc[4][4];
#pragma unroll
  for (int i=0;i<4;i++)
#pragma unroll
    for (int j=0;j<4;j++){ f32x4 z = {0.f,0.f,0.f,0.f}; acc[i][j] = z; }

  for (int tap = 0; tap < 9; ++tap){
    int ky = tap/3, kx = tap%3;
    float offy = offs[(bh*64 + px)*18 + 2*tap];
    float offx = offs[(bh*64 + px)*18 + 2*tap + 1];
    float y = (float)(h + ky - 1) + offy;
    float x = (float)(px + kx - 1) + offx;
    float y0f = floorf(y), x0f = floorf(x);
    float wy1 = y - y0f, wx1 = x - x0f;
    float wy0 = 1.f - wy1, wx0 = 1.f - wx1;
    int iy0 = iclampi((int)y0f, -4, 67), ix0 = iclampi((int)x0f, -4, 67);
    int iy1 = iclampi((int)y0f + 1, -4, 67), ix1 = iclampi((int)x0f + 1, -4, 67);
    const u16* p00 = x2pad + (((b*72 + iy0+4)*72) + (ix0+4))*256 + cg*64;
    const u16* p01 = x2pad + (((b*72 + iy0+4)*72) + (ix1+4))*256 + cg*64;
    const u16* p10 = x2pad + (((b*72 + iy1+4)*72) + (ix0+4))*256 + cg*64;
    const u16* p11 = x2pad + (((b*72 + iy1+4)*72) + (ix1+4))*256 + cg*64;
    float w00 = wy0*wx0, w01 = wy0*wx1, w10 = wy1*wx0, w11 = wy1*wx1;
#pragma unroll
    for (int u = 0; u < 8; ++u){
      int4 v00 = *(const int4*)(p00 + u*8);
      int4 v01 = *(const int4*)(p01 + u*8);
      int4 v10 = *(const int4*)(p10 + u*8);
      int4 v11 = *(const int4*)(p11 + u*8);
      float a00[8], a01[8], a10[8], a11[8];
      unpack8(v00,a00); unpack8(v01,a01); unpack8(v10,a10); unpack8(v11,a11);
      union { u16 h2[8]; int4 v; } R;
#pragma unroll
      for (int jj = 0; jj < 8; ++jj)
        R.h2[jj] = f2bf(w00*a00[jj] + w01*a01[jj] + w10*a10[jj] + w11*a11[jj]);
      int ch = cg*64 + u*8;
      int ks = ch >> 5, q = (ch >> 3) & 3;
      *(int4*)(lA + (((ks*4 + mt_s)*4 + q)*16 + ml_s)*8) = R.v;
    }
    __syncthreads();
#pragma unroll
    for (int ks = 0; ks < 8; ++ks){
      bf16x8 bv[4];
#pragma unroll
      for (int ni=0; ni<4; ++ni){
        int n = wave*64 + ni*16 + l15;
        bv[ni] = *(const bf16x8*)(walign + n*2304 + tap*256 + ks*32 + quad*8);
      }
#pragma unroll
      for (int mi=0; mi<4; ++mi){
        bf16x8 av = *(const bf16x8*)(lA + (((ks*4 + mi)*4 + quad)*16 + l15)*8);
#pragma unroll
        for (int ni=0; ni<4; ++ni) acc[mi][ni] = MFMA16x16x32(av, bv[ni], acc[mi][ni]);
      }
    }
    __syncthreads();
  }
#pragma unroll
  for (int mi=0; mi<4; ++mi){
#pragma unroll
    for (int ni=0; ni<4; ++ni){
      int n = wave*64 + ni*16 + l15;
#pragma unroll
      for (int r=0; r<4; ++r){
        int m = mi*16 + quad*4 + r;
        stacked[(((b*66 + h+1)*66) + (m+1))*512 + 256 + n] = f2bf(acc[mi][ni][r]);
      }
    }
  }
}

// ---------------------------------------------------------------------------
// 3x3 conv as implicit GEMM, m97 geometry: 128px x 128n tile, 256 threads
// (2x2 waves, 4x4 acc each), K-step 64, single-buffered 32 KB LDS,
// 2-barrier K-loop, 3 blocks/CU. blockIdx = mb*NBLK + nb (nb in low bits ->
// per-XCD constant weight slice).
template<int NBLK, bool STATS>
__global__ __launch_bounds__(256, 3) void k_conv128(const u16* __restrict__ in,
    const u16* __restrict__ wts, const float* __restrict__ bias,
    u16* __restrict__ out, float* __restrict__ partials){
  __shared__ u16 lA[8192];  // [ks2][mt8][quad][l15][8]
  __shared__ u16 lB[8192];  // [ks2][nt8][quad][l15][8]
  const int NOUT = NBLK * 128;
  int tid = threadIdx.x;
  int nb = blockIdx.x & (NBLK - 1);
  int mb = blockIdx.x / NBLK;
  int b = mb >> 5, h0 = (mb & 31) * 2;
  int wave = tid >> 6, lane = tid & 63, l15 = lane & 15, quad = lane >> 4;
  int wm = wave & 1, wn = wave >> 1;
  f32x4 acc[4][4];
#pragma unroll
  for (int i=0;i<4;i++)
#pragma unroll
    for (int j=0;j<4;j++){ f32x4 z = {0.f,0.f,0.f,0.f}; acc[i][j] = z; }

  for (int tap = 0; tap < 9; ++tap){
    int ky = tap / 3, kx = tap % 3;
    const u16* inrow = in + ((b*66 + h0 + ky)*66 + kx)*512;
    const u16* wtap  = wts + tap*512;
    for (int ksin = 0; ksin < 8; ++ksin){
      int kc = ksin * 64;
      // stage A (128px x 64ch) + B (128n x 64ch), frag-ordered
#pragma unroll
      for (int i = 0; i < 4; ++i){
        int j = tid + i*256;
        int l = j & 15, qq = (j >> 4) & 3, t8 = (j >> 6) & 7, ks2 = j >> 9;
        int px = t8*16 + l, r = px >> 6, w = px & 63;
        g2l16(inrow + (r*66 + w)*512 + kc + ks2*32 + qq*8, lA + j*8);
        int n = nb*128 + t8*16 + l;
        g2l16(wtap + n*4608 + kc + ks2*32 + qq*8, lB + j*8);
      }
      __syncthreads();
#pragma unroll
      for (int ks2 = 0; ks2 < 2; ++ks2){
        bf16x8 bv[4];
#pragma unroll
        for (int ni=0; ni<4; ++ni)
          bv[ni] = *(const bf16x8*)(lB + (((ks2*8 + wn*4 + ni)*4 + quad)*16 + l15)*8);
#pragma unroll
        for (int mi=0; mi<4; ++mi){
          bf16x8 av = *(const bf16x8*)(lA + (((ks2*8 + wm*4 + mi)*4 + quad)*16 + l15)*8);
#pragma unroll
          for (int ni=0; ni<4; ++ni) acc[mi][ni] = MFMA16x16x32(av, bv[ni], acc[mi][ni]);
        }
      }
      __syncthreads();
    }
  }

  float sc = 0.f, ss = 0.f, sq = 0.f;
#pragma unroll
  for (int mi=0; mi<4; ++mi){
#pragma unroll
    for (int ni=0; ni<4; ++ni){
      int n = nb*128 + wn*64 + ni*16 + l15;
      float bvl = bias[n];
#pragma unroll
      for (int r=0; r<4; ++r){
        int m = wm*64 + mi*16 + quad*4 + r;
        int row = h0 + (m >> 6), w = m & 63;
        float v = acc[mi][ni][r] + bvl;
        v = fmaxf(v, 0.f);
        out[(((b*64 + row)*64) + w)*NOUT + n] = f2bf(v);
        if (STATS){ sc += (v > 0.f) ? 1.f : 0.f; ss += v; sq += v*v; }
      }
    }
  }
  if constexpr (STATS){
    __shared__ float red[4][3];
#pragma unroll
    for (int off = 32; off; off >>= 1){
      sc += __shfl_down(sc, off); ss += __shfl_down(ss, off); sq += __shfl_down(sq, off);
    }
    if (lane == 0){ red[wave][0]=sc; red[wave][1]=ss; red[wave][2]=sq; }
    __syncthreads();
    if (tid == 0){
      float a0=0,a1=0,a2=0;
      for (int w2=0; w2<4; ++w2){ a0+=red[w2][0]; a1+=red[w2][1]; a2+=red[w2][2]; }
      partials[blockIdx.x*3+0]=a0; partials[blockIdx.x*3+1]=a1; partials[blockIdx.x*3+2]=a2;
    }
  }
}

// ---------------------------------------------------------------------------
// Reduce 1024 per-block partials; (blockIdx&3)<2 -> update, else reset.
__global__ __launch_bounds__(256) void k_finalize(const float* __restrict__ partials,
                                                  float* __restrict__ ubs){
  __shared__ float red[4][6];
  int tid = threadIdx.x, lane = tid & 63, wave = tid >> 6;
  int g = ((tid & 3) < 2) ? 0 : 1;  // stride-256 walk keeps i&3 == tid&3
  float c=0.f, s=0.f, q=0.f;
  for (int i = tid; i < 1024; i += 256){
    c += partials[i*3+0]; s += partials[i*3+1]; q += partials[i*3+2];
  }
  float cu = g==0 ? c : 0.f, su = g==0 ? s : 0.f, qu = g==0 ? q : 0.f;
  float cr = g==1 ? c : 0.f, sr = g==1 ? s : 0.f, qr = g==1 ? q : 0.f;
#pragma unroll
  for (int off = 32; off; off >>= 1){
    cu += __shfl_down(cu, off); su += __shfl_down(su, off); qu += __shfl_down(qu, off);
    cr += __shfl_down(cr, off); sr += __shfl_down(sr, off); qr += __shfl_down(qr, off);
  }
  if (lane == 0){ red[wave][0]=cu; red[wave][1]=su; red[wave][2]=qu;
                  red[wave][3]=cr; red[wave][4]=sr; red[wave][5]=qr; }
  __syncthreads();
  if (tid < 2){
    double C=0, S=0, Q=0;
    for (int w2=0; w2<4; ++w2){
      C += red[w2][tid*3+0]; S += red[w2][tid*3+1]; Q += red[w2][tid*3+2];
    }
    float ub = 1.f;
    if (C >= 2.0){
      double mean = S / C;
      double var = (Q - C*mean*mean) / (C - 1.0);
      if (var < 0.0) var = 0.0;
      ub = (float)(mean + 3.0*sqrt(var));
    }
    ubs[tid] = ub;
    ubs[2+tid] = 1.f/ub;
  }
}

// stacked2[...,256:512] = bf16(in_state * min(reset,ub_r)/ub_r)
__global__ __launch_bounds__(256) void k_mulreset(const u16* __restrict__ G,
    const u16* __restrict__ x2pad, const float* __restrict__ ubs,
    u16* __restrict__ stacked2){
  int tid = threadIdx.x, bh = blockIdx.x;
  int b = bh >> 6, h = bh & 63;
  int px = tid >> 2, cg = tid & 3;
  float ubr = ubs[1], inv = ubs[3];
#pragma unroll
  for (int u = 0; u < 8; ++u){
    int c = cg*64 + u*8;
    int4 gv = *(const int4*)(G + (bh*64 + px)*512 + 256 + c);
    int4 sv = *(const int4*)(x2pad + (((b*72 + h+4)*72) + (px+4))*256 + c);
    float gf[8], sf[8]; unpack8(gv, gf); unpack8(sv, sf);
    union { u16 h2[8]; int4 v; } R;
#pragma unroll
    for (int j=0;j<8;j++){
      float r = fminf(gf[j], ubr) * inv;
      R.h2[j] = f2bf(sf[j] * r);
    }
    *(int4*)(stacked2 + (((b*66 + h+1)*66) + (px+1))*512 + 256 + c) = R.v;
  }
}

// new_state = s*(1-u) + o*u, NCHW fp32 out (x2 copies), via LDS transpose.
__global__ __launch_bounds__(256) void k_final(const u16* __restrict__ G,
    const u16* __restrict__ O, const float* __restrict__ in_state,
    const float* __restrict__ ubs, float* __restrict__ dout){
  __shared__ float Q[64*65];
  __shared__ float P[64*65];
  int tid = threadIdx.x, bh = blockIdx.x;
  int b = bh >> 6, h = bh & 63;
  float ubu = ubs[0], inv = ubs[2];
  int px = tid >> 2, cs = (tid & 3)*16;
  int w = tid & 63, c4 = tid >> 6;
  for (int cb = 0; cb < 4; ++cb){
#pragma unroll
    for (int tt = 0; tt < 2; ++tt){
      int cl = cs + tt*8;
      int c = cb*64 + cl;
      int4 gv = *(const int4*)(G + (bh*64 + px)*512 + c);
      int4 ov = *(const int4*)(O + (bh*64 + px)*256 + c);
      float gf[8], of[8]; unpack8(gv, gf); unpack8(ov, of);
#pragma unroll
      for (int j=0;j<8;j++){
        float u = fminf(gf[j], ubu) * inv;
        Q[px*65 + cl + j] = u;
        P[px*65 + cl + j] = of[j]*u;
      }
    }
    __syncthreads();
    for (int i = 0; i < 16; ++i){
      int cl = i*4 + c4;
      int c = cb*64 + cl;
      int gidx = (((b*256 + c)*64) + h)*64 + w;
      float s = in_state[gidx];
      float v = s*(1.f - Q[w*65 + cl]) + P[w*65 + cl];
      dout[gidx] = v;
      dout[8388608 + gidx] = v;
    }
    __syncthreads();
  }
}

// ---------------------------------------------------------------------------
extern "C" void kernel_launch(void* const* d_in, const int* in_sizes, int n_in,
                              void* d_out, int out_size, void* d_ws, size_t ws_size,
                              hipStream_t stream){
  (void)in_sizes; (void)n_in; (void)out_size; (void)ws_size;
  const float* inputs   = (const float*)d_in[0];
  const float* in_state = (const float*)d_in[1];
  const float* w_reset  = (const float*)d_in[2];
  const float* b_reset  = (const float*)d_in[3];
  const float* w_update = (const float*)d_in[4];
  const float* b_update = (const float*)d_in[5];
  const float* w_out    = (const float*)d_in[6];
  const float* b_out    = (const float*)d_in[7];
  const float* w_offset = (const float*)d_in[8];
  const float* w_align  = (const float*)d_in[9];
  float* dout = (float*)d_out;

  char* ws = (char*)d_ws;
  size_t off = 0;
  auto alloc = [&](size_t bytes)->char*{
    char* p = ws + off; off = (off + bytes + 255) & ~(size_t)255; return p;
  };
  const size_t x2pad_b   = 8ull*72*72*256*2;
  const size_t stacked_b = 8ull*66*66*512*2;
  u16* x2pad    = (u16*)alloc(x2pad_b);
  u16* stacked  = (u16*)alloc(stacked_b);
  u16* stacked2 = (u16*)alloc(stacked_b);
  float* corr   = (float*)alloc(8ull*64*64*81*4);
  float* offs   = (float*)alloc(8ull*64*64*18*4);
  u16* G        = (u16*)alloc(8ull*64*64*512*2);
  u16* O        = (u16*)alloc(8ull*64*64*256*2);
  u16* wgate    = (u16*)alloc(512ull*4608*2);
  u16* woutb    = (u16*)alloc(256ull*4608*2);
  u16* walignb  = (u16*)alloc(256ull*2304*2);
  float* woff   = (float*)alloc(1458*4);
  float* biascat= (float*)alloc(512*4);
  float* partials=(float*)alloc(1024*3*4);
  float* ubs    = (float*)alloc(4*4);

  // zero only the padding rings (interiors are fully overwritten)
  k_ring<<<520, 256, 0, stream>>>(stacked, 66, 1, 512);
  k_ring<<<520, 256, 0, stream>>>(stacked2, 66, 1, 512);
  k_ring<<<1088, 256, 0, stream>>>(x2pad, 72, 4, 256);

  k_repack<<<9216, 256, 0, stream>>>(w_reset, b_reset, w_update, b_update, w_out,
                                     w_offset, w_align, wgate, woutb, walignb, woff, biascat);
  k_transform<<<512, 256, 0, stream>>>(inputs, in_state, stacked, stacked2, x2pad);
  k_corr<<<512, 256, 0, stream>>>(stacked, x2pad, corr);
  k_offset<<<1024, 256, 0, stream>>>(corr, woff, offs);
  k_deform<<<512, 256, 0, stream>>>(x2pad, offs, walignb, stacked);
  k_conv128<4,true><<<1024, 256, 0, stream>>>(stacked, wgate, biascat, G, partials);
  k_finalize<<<1, 256, 0, stream>>>(partials, ubs);
  k_mulreset<<<512, 256, 0, stream>>>(G, x2pad, ubs, stacked2);
  k_conv128<2,false><<<512, 256, 0, stream>>>(stacked2, woutb, b_out, O, nullptr);
  k_final<<<512, 256, 0, stream>>>(G, O, in_state, ubs, dout);
}

// Round 4
// 725.704 us; speedup vs baseline: 1.1388x; 1.1388x over previous
//
#include <hip/hip_runtime.h>
#include <stdint.h>
#include <math.h>

typedef unsigned short u16;
typedef short bf16x8 __attribute__((ext_vector_type(8)));
typedef float f32x4 __attribute__((ext_vector_type(4)));

#define MFMA16x16x32(a,b,c) __builtin_amdgcn_mfma_f32_16x16x32_bf16((a),(b),(c),0,0,0)

typedef __attribute__((address_space(3))) void as3_void;
typedef const __attribute__((address_space(1))) void as1_void;

__device__ __forceinline__ void g2l16(const void* g, void* l){
#if __has_builtin(__builtin_amdgcn_global_load_lds)
  __builtin_amdgcn_global_load_lds((as1_void*)g, (as3_void*)l, 16, 0, 0);
#else
  *(int4*)l = *(const int4*)g;
#endif
}

__device__ __forceinline__ u16 f2bf(float f){
  uint32_t u = __builtin_bit_cast(uint32_t, f);
  u += 0x7fffu + ((u >> 16) & 1u);
  return (u16)(u >> 16);
}
__device__ __forceinline__ float bf2f(u16 h){
  uint32_t u = ((uint32_t)h) << 16;
  return __builtin_bit_cast(float, u);
}
__device__ __forceinline__ void unpack8(int4 v, float* o){
  uint32_t w0=(uint32_t)v.x, w1=(uint32_t)v.y, w2=(uint32_t)v.z, w3=(uint32_t)v.w;
  o[0]=__builtin_bit_cast(float, w0<<16); o[1]=__builtin_bit_cast(float, w0&0xffff0000u);
  o[2]=__builtin_bit_cast(float, w1<<16); o[3]=__builtin_bit_cast(float, w1&0xffff0000u);
  o[4]=__builtin_bit_cast(float, w2<<16); o[5]=__builtin_bit_cast(float, w2&0xffff0000u);
  o[6]=__builtin_bit_cast(float, w3<<16); o[7]=__builtin_bit_cast(float, w3&0xffff0000u);
}
__device__ __forceinline__ int iclampi(int v,int lo,int hi){ return v<lo?lo:(v>hi?hi:v); }

// ---------------------------------------------------------------------------
// Repack weights frag-packed per K-step-64 chunk: chunk index (kk*NBLK + nb),
// kk = tap*8 + ksin, chunk = 1024 slots j x 8 elems. Slot j: l=j&15,
// q=(j>>4)&3, t8=(j>>6)&7, ks2=j>>9 -> n = nb*128 + t8*16 + l,
// c = ksin*64 + ks2*32 + q*8 + e. B staging reads contiguous 16 KB chunks.
__global__ void k_repack(const float* __restrict__ w_reset, const float* __restrict__ b_reset,
                         const float* __restrict__ w_update, const float* __restrict__ b_update,
                         const float* __restrict__ w_out, const float* __restrict__ w_offset,
                         const float* __restrict__ w_align,
                         u16* __restrict__ wgate, u16* __restrict__ wout,
                         u16* __restrict__ walign, float* __restrict__ woff,
                         float* __restrict__ biascat){
  int idx = blockIdx.x * 256 + threadIdx.x;
  if (idx < 512*4608){           // gate: NBLK=4
    int e = idx & 7, j = (idx >> 3) & 1023, nb = (idx >> 13) & 3, kk = idx >> 15;
    int l = j & 15, q = (j >> 4) & 3, t8 = (j >> 6) & 7, ks2 = j >> 9;
    int n = nb*128 + t8*16 + l;
    int tap = kk >> 3, ksin = kk & 7;
    int c = ksin*64 + ks2*32 + q*8 + e;
    int ky = tap/3, kx = tap%3;
    float v = (n < 256) ? w_update[((n*512 + c)*3 + ky)*3 + kx]
                        : w_reset[(((n-256)*512 + c)*3 + ky)*3 + kx];
    wgate[idx] = f2bf(v);
  }
  if (idx < 256*4608){           // out: NBLK=2
    int e = idx & 7, j = (idx >> 3) & 1023, nb = (idx >> 13) & 1, kk = idx >> 14;
    int l = j & 15, q = (j >> 4) & 3, t8 = (j >> 6) & 7, ks2 = j >> 9;
    int n = nb*128 + t8*16 + l;
    int tap = kk >> 3, ksin = kk & 7;
    int c = ksin*64 + ks2*32 + q*8 + e;
    int ky = tap/3, kx = tap%3;
    wout[idx] = f2bf(w_out[((n*512 + c)*3 + ky)*3 + kx]);
  }
  if (idx < 256*2304){           // align (k_deform reads directly)
    int n = idx / 2304, k = idx % 2304;
    int tap = k >> 8, c = k & 255;
    int ky = tap/3, kx = tap%3;
    walign[idx] = f2bf(w_align[((n*256 + c)*3 + ky)*3 + kx]);
  }
  if (idx < 1458) woff[idx] = w_offset[idx] * (1.f/256.f);
  if (idx < 512) biascat[idx] = (idx < 256) ? b_update[idx] : b_reset[idx-256];
}

// ---------------------------------------------------------------------------
// NCHW fp32 -> NHWC bf16.
__global__ __launch_bounds__(256) void k_transform(const float* __restrict__ inputs,
    const float* __restrict__ in_state, u16* __restrict__ stacked,
    u16* __restrict__ stacked2, u16* __restrict__ x2pad){
  __shared__ u16 t1[64*264];
  __shared__ u16 t2[64*264];
  int tid = threadIdx.x, bh = blockIdx.x;
  int b = bh >> 6, h = bh & 63;
  int w = tid & 63, cq = tid >> 6;
  for (int i = 0; i < 64; ++i){
    int c = i*4 + cq;
    int gi = ((b*256 + c)*64 + h)*64 + w;
    t1[w*264 + c] = f2bf(inputs[gi]);
    t2[w*264 + c] = f2bf(in_state[gi]);
  }
  __syncthreads();
  int px = tid >> 2, cg = tid & 3;
#pragma unroll
  for (int u = 0; u < 8; ++u){
    int c = cg*64 + u*8;
    int4 v1 = *(const int4*)(t1 + px*264 + c);
    int4 v2 = *(const int4*)(t2 + px*264 + c);
    *(int4*)(stacked  + (((b*66 + h+1)*66) + (px+1))*512 + c) = v1;
    *(int4*)(stacked2 + (((b*66 + h+1)*66) + (px+1))*512 + c) = v1;
    *(int4*)(x2pad    + (((b*72 + h+4)*72) + (px+4))*256 + c) = v2;
  }
}

// ---------------------------------------------------------------------------
// Correlation as masked local GEMM.
__global__ __launch_bounds__(256) void k_corr(const u16* __restrict__ stacked,
    const u16* __restrict__ x2pad, float* __restrict__ corr){
  __shared__ u16 lA[8192];
  __shared__ u16 lB[32768];
  int tid = threadIdx.x, idx = blockIdx.x;
  int b = idx >> 6, ty = (idx >> 3) & 7, tx = idx & 7;
  int h0 = ty*8, w0 = tx*8;
  int wave = tid >> 6, lane = tid & 63, l15 = lane & 15, quad = lane >> 4;
  f32x4 acc[4][4];
#pragma unroll
  for (int i=0;i<4;i++)
#pragma unroll
    for (int j=0;j<4;j++){ f32x4 z = {0.f,0.f,0.f,0.f}; acc[i][j] = z; }

  for (int s = 0; s < 2; ++s){
#pragma unroll
    for (int i = 0; i < 4; ++i){
      int j = tid + i*256;
      int ml = j & 15, q = (j>>4)&3, mt = (j>>6)&3, ks = j >> 8;
      int px = mt*16 + ml, py = px >> 3, pxx = px & 7;
      const u16* g = stacked + (((b*66 + h0+py+1)*66) + (w0+pxx+1))*512 + s*128 + ks*32 + q*8;
      g2l16(g, lA + j*8);
    }
#pragma unroll
    for (int i = 0; i < 16; ++i){
      int j = tid + i*256;
      int nl = j & 15, q = (j>>4)&3, nt = (j>>6)&15, ks = j >> 10;
      int qp = nt*16 + nl, qy = qp >> 4, qx = qp & 15;
      const u16* g = x2pad + (((b*72 + h0+qy)*72) + (w0+qx))*256 + s*128 + ks*32 + q*8;
      g2l16(g, lB + j*8);
    }
    __syncthreads();
#pragma unroll
    for (int ks = 0; ks < 4; ++ks){
      bf16x8 bv[4];
#pragma unroll
      for (int ni=0; ni<4; ++ni){
        int nt = wave*4 + ni;
        bv[ni] = *(const bf16x8*)(lB + (((ks*16 + nt)*4 + quad)*16 + l15)*8);
      }
#pragma unroll
      for (int mi=0; mi<4; ++mi){
        bf16x8 av = *(const bf16x8*)(lA + (((ks*4 + mi)*4 + quad)*16 + l15)*8);
#pragma unroll
        for (int ni=0; ni<4; ++ni) acc[mi][ni] = MFMA16x16x32(av, bv[ni], acc[mi][ni]);
      }
    }
    __syncthreads();
  }
#pragma unroll
  for (int mi=0; mi<4; ++mi){
#pragma unroll
    for (int ni=0; ni<4; ++ni){
      int n = wave*64 + ni*16 + l15;
      int qy = n >> 4, qx = n & 15;
#pragma unroll
      for (int r=0; r<4; ++r){
        int m = mi*16 + quad*4 + r;
        int py = m >> 3, pxx = m & 7;
        int dy = qy - py, dx = qx - pxx;
        if ((unsigned)dy <= 8u && (unsigned)dx <= 8u)
          corr[(((b*64 + h0+py)*64) + (w0+pxx))*81 + dy*9 + dx] = acc[mi][ni][r];
      }
    }
  }
}

// ---------------------------------------------------------------------------
__global__ __launch_bounds__(256) void k_offset(const float* __restrict__ corr,
    const float* __restrict__ woff, float* __restrict__ offs){
  __shared__ float lc[32*84];
  __shared__ float lw[18*84];
  int tid = threadIdx.x, blk = blockIdx.x;
  int row = blk >> 1, half = blk & 1;
  int base = row*5184 + half*32*81;
  for (int i = tid; i < 32*81; i += 256){
    int px = i / 81, d = i % 81;
    lc[px*84 + d] = corr[base + i];
  }
  for (int i = tid; i < 18*84; i += 256){
    int o = i / 84, d = i % 84;
    if (d < 81) lw[i] = woff[o*81 + d];
  }
  __syncthreads();
  int px = tid & 31, og = tid >> 5;
  for (int o = og; o < 18; o += 8){
    float s = 0.f;
#pragma unroll
    for (int dd = 0; dd < 20; ++dd){
      float4 a = *(const float4*)(lc + px*84 + dd*4);
      float4 wv = *(const float4*)(lw + o*84 + dd*4);
      s += a.x*wv.x + a.y*wv.y + a.z*wv.z + a.w*wv.w;
    }
    s += lc[px*84 + 80] * lw[o*84 + 80];
    offs[(row*64 + half*32 + px)*18 + o] = s;
  }
}

// ---------------------------------------------------------------------------
// Deformable conv (unchanged).
__global__ __launch_bounds__(256) void k_deform(const u16* __restrict__ x2pad,
    const float* __restrict__ offs, const u16* __restrict__ walign,
    u16* __restrict__ stacked){
  __shared__ u16 lA[16384];
  int tid = threadIdx.x, bh = blockIdx.x;
  int b = bh >> 6, h = bh & 63;
  int wave = tid >> 6, lane = tid & 63, l15 = lane & 15, quad = lane >> 4;
  int px = tid >> 2, cg = tid & 3;
  int mt_s = px >> 4, ml_s = px & 15;
  f32x4 acc[4][4];
#pragma unroll
  for (int i=0;i<4;i++)
#pragma unroll
    for (int j=0;j<4;j++){ f32x4 z = {0.f,0.f,0.f,0.f}; acc[i][j] = z; }

  for (int tap = 0; tap < 9; ++tap){
    int ky = tap/3, kx = tap%3;
    float offy = offs[(bh*64 + px)*18 + 2*tap];
    float offx = offs[(bh*64 + px)*18 + 2*tap + 1];
    float y = (float)(h + ky - 1) + offy;
    float x = (float)(px + kx - 1) + offx;
    float y0f = floorf(y), x0f = floorf(x);
    float wy1 = y - y0f, wx1 = x - x0f;
    float wy0 = 1.f - wy1, wx0 = 1.f - wx1;
    int iy0 = iclampi((int)y0f, -4, 67), ix0 = iclampi((int)x0f, -4, 67);
    int iy1 = iclampi((int)y0f + 1, -4, 67), ix1 = iclampi((int)x0f + 1, -4, 67);
    const u16* p00 = x2pad + (((b*72 + iy0+4)*72) + (ix0+4))*256 + cg*64;
    const u16* p01 = x2pad + (((b*72 + iy0+4)*72) + (ix1+4))*256 + cg*64;
    const u16* p10 = x2pad + (((b*72 + iy1+4)*72) + (ix0+4))*256 + cg*64;
    const u16* p11 = x2pad + (((b*72 + iy1+4)*72) + (ix1+4))*256 + cg*64;
    float w00 = wy0*wx0, w01 = wy0*wx1, w10 = wy1*wx0, w11 = wy1*wx1;
#pragma unroll
    for (int u = 0; u < 8; ++u){
      int4 v00 = *(const int4*)(p00 + u*8);
      int4 v01 = *(const int4*)(p01 + u*8);
      int4 v10 = *(const int4*)(p10 + u*8);
      int4 v11 = *(const int4*)(p11 + u*8);
      float a00[8], a01[8], a10[8], a11[8];
      unpack8(v00,a00); unpack8(v01,a01); unpack8(v10,a10); unpack8(v11,a11);
      union { u16 h2[8]; int4 v; } R;
#pragma unroll
      for (int jj = 0; jj < 8; ++jj)
        R.h2[jj] = f2bf(w00*a00[jj] + w01*a01[jj] + w10*a10[jj] + w11*a11[jj]);
      int ch = cg*64 + u*8;
      int ks = ch >> 5, q = (ch >> 3) & 3;
      *(int4*)(lA + (((ks*4 + mt_s)*4 + q)*16 + ml_s)*8) = R.v;
    }
    __syncthreads();
#pragma unroll
    for (int ks = 0; ks < 8; ++ks){
      bf16x8 bv[4];
#pragma unroll
      for (int ni=0; ni<4; ++ni){
        int n = wave*64 + ni*16 + l15;
        bv[ni] = *(const bf16x8*)(walign + n*2304 + tap*256 + ks*32 + quad*8);
      }
#pragma unroll
      for (int mi=0; mi<4; ++mi){
        bf16x8 av = *(const bf16x8*)(lA + (((ks*4 + mi)*4 + quad)*16 + l15)*8);
#pragma unroll
        for (int ni=0; ni<4; ++ni) acc[mi][ni] = MFMA16x16x32(av, bv[ni], acc[mi][ni]);
      }
    }
    __syncthreads();
  }
#pragma unroll
  for (int mi=0; mi<4; ++mi){
#pragma unroll
    for (int ni=0; ni<4; ++ni){
      int n = wave*64 + ni*16 + l15;
#pragma unroll
      for (int r=0; r<4; ++r){
        int m = mi*16 + quad*4 + r;
        stacked[(((b*66 + h+1)*66) + (m+1))*512 + 256 + n] = f2bf(acc[mi][ni][r]);
      }
    }
  }
}

// ---------------------------------------------------------------------------
// 3x3 conv, implicit GEMM, round-2's proven barrier structure (single-buffer
// stage -> barrier -> compute -> barrier), K-step 64, 128px x 128n tile.
// New vs round 2 (index math only): XCD-batch swizzle (b = g&7 -> each XCD's
// L2 holds one batch image) and frag-packed contiguous weight chunks.
template<int NBLK, bool STATS>
__global__ __launch_bounds__(256, 4) void k_conv128(const u16* __restrict__ in,
    const u16* __restrict__ wts2, const float* __restrict__ bias,
    u16* __restrict__ out, float* __restrict__ partials){
  __shared__ u16 lA[8192];  // 128 px x 64 ch, frag-ordered
  __shared__ u16 lB[8192];  // 128 n  x 64 ch, frag-ordered
  const int NOUT = NBLK * 128;
  int tid = threadIdx.x, g = blockIdx.x;
  int b = g & 7, rr = (g >> 3) & 31, nb = g >> 8;
  int h0 = rr * 2;
  int wave = tid >> 6, lane = tid & 63, l15 = lane & 15, quad = lane >> 4;
  int wm = wave & 1, wn = wave >> 1;
  f32x4 acc[4][4];
#pragma unroll
  for (int i=0;i<4;i++)
#pragma unroll
    for (int j=0;j<4;j++){ f32x4 z = {0.f,0.f,0.f,0.f}; acc[i][j] = z; }

  for (int tap = 0; tap < 9; ++tap){
    int ky = tap / 3, kx = tap % 3;
    const u16* inrow = in + ((b*66 + h0 + ky)*66 + kx)*512;
    const u16* wbase = wts2 + (size_t)(tap*8*NBLK + nb)*8192;
    for (int ksin = 0; ksin < 8; ++ksin){
      const u16* wchunk = wbase + (size_t)ksin*NBLK*8192;
#pragma unroll
      for (int i = 0; i < 4; ++i){
        int j = tid + i*256;
        int l = j & 15, q = (j >> 4) & 3, t8 = (j >> 6) & 7, ks2 = j >> 9;
        int px = t8*16 + l, r = px >> 6, w = px & 63;
        g2l16(inrow + (r*66 + w)*512 + ksin*64 + ks2*32 + q*8, lA + j*8);
        g2l16(wchunk + j*8, lB + j*8);
      }
      __syncthreads();
#pragma unroll
      for (int ks2 = 0; ks2 < 2; ++ks2){
        bf16x8 bv[4];
#pragma unroll
        for (int ni=0; ni<4; ++ni)
          bv[ni] = *(const bf16x8*)(lB + (((ks2*8 + wn*4 + ni)*4 + quad)*16 + l15)*8);
#pragma unroll
        for (int mi=0; mi<4; ++mi){
          bf16x8 av = *(const bf16x8*)(lA + (((ks2*8 + wm*4 + mi)*4 + quad)*16 + l15)*8);
#pragma unroll
          for (int ni=0; ni<4; ++ni) acc[mi][ni] = MFMA16x16x32(av, bv[ni], acc[mi][ni]);
        }
      }
      __syncthreads();
    }
  }

  float sc = 0.f, ss = 0.f, sq = 0.f;
#pragma unroll
  for (int mi=0; mi<4; ++mi){
#pragma unroll
    for (int ni=0; ni<4; ++ni){
      int n = nb*128 + wn*64 + ni*16 + l15;
      float bvl = bias[n];
#pragma unroll
      for (int r=0; r<4; ++r){
        int m = wm*64 + mi*16 + quad*4 + r;
        int row = h0 + (m >> 6), w = m & 63;
        float v = acc[mi][ni][r] + bvl;
        v = fmaxf(v, 0.f);
        out[(((b*64 + row)*64) + w)*NOUT + n] = f2bf(v);
        if (STATS){ sc += (v > 0.f) ? 1.f : 0.f; ss += v; sq += v*v; }
      }
    }
  }
  if constexpr (STATS){
    __shared__ float red[4][3];
#pragma unroll
    for (int off = 32; off; off >>= 1){
      sc += __shfl_down(sc, off); ss += __shfl_down(ss, off); sq += __shfl_down(sq, off);
    }
    if (lane == 0){ red[wave][0]=sc; red[wave][1]=ss; red[wave][2]=sq; }
    __syncthreads();
    if (tid == 0){
      float a0=0,a1=0,a2=0;
      for (int w2=0; w2<4; ++w2){ a0+=red[w2][0]; a1+=red[w2][1]; a2+=red[w2][2]; }
      partials[blockIdx.x*3+0]=a0; partials[blockIdx.x*3+1]=a1; partials[blockIdx.x*3+2]=a2;
    }
  }
}

// ---------------------------------------------------------------------------
// Reduce 1024 per-block partials; nb = blockIdx>>8 -> update for i<512.
__global__ __launch_bounds__(256) void k_finalize(const float* __restrict__ partials,
                                                  float* __restrict__ ubs){
  __shared__ float red[4][6];
  int tid = threadIdx.x, lane = tid & 63, wave = tid >> 6;
  float cu=0,su=0,qu=0,cr=0,sr=0,qr=0;
  for (int j = 0; j < 4; ++j){
    int i = tid + j*256;
    float c = partials[i*3+0], s = partials[i*3+1], q = partials[i*3+2];
    if (j < 2){ cu+=c; su+=s; qu+=q; } else { cr+=c; sr+=s; qr+=q; }
  }
#pragma unroll
  for (int off = 32; off; off >>= 1){
    cu += __shfl_down(cu, off); su += __shfl_down(su, off); qu += __shfl_down(qu, off);
    cr += __shfl_down(cr, off); sr += __shfl_down(sr, off); qr += __shfl_down(qr, off);
  }
  if (lane == 0){ red[wave][0]=cu; red[wave][1]=su; red[wave][2]=qu;
                  red[wave][3]=cr; red[wave][4]=sr; red[wave][5]=qr; }
  __syncthreads();
  if (tid < 2){
    double C=0, S=0, Q=0;
    for (int w2=0; w2<4; ++w2){
      C += red[w2][tid*3+0]; S += red[w2][tid*3+1]; Q += red[w2][tid*3+2];
    }
    float ub = 1.f;
    if (C >= 2.0){
      double mean = S / C;
      double var = (Q - C*mean*mean) / (C - 1.0);
      if (var < 0.0) var = 0.0;
      ub = (float)(mean + 3.0*sqrt(var));
    }
    ubs[tid] = ub;
    ubs[2+tid] = 1.f/ub;
  }
}

// stacked2[...,256:512] = bf16(in_state * min(reset,ub_r)/ub_r)
__global__ __launch_bounds__(256) void k_mulreset(const u16* __restrict__ G,
    const u16* __restrict__ x2pad, const float* __restrict__ ubs,
    u16* __restrict__ stacked2){
  int tid = threadIdx.x, bh = blockIdx.x;
  int b = bh >> 6, h = bh & 63;
  int px = tid >> 2, cg = tid & 3;
  float ubr = ubs[1], inv = ubs[3];
#pragma unroll
  for (int u = 0; u < 8; ++u){
    int c = cg*64 + u*8;
    int4 gv = *(const int4*)(G + (bh*64 + px)*512 + 256 + c);
    int4 sv = *(const int4*)(x2pad + (((b*72 + h+4)*72) + (px+4))*256 + c);
    float gf[8], sf[8]; unpack8(gv, gf); unpack8(sv, sf);
    union { u16 h2[8]; int4 v; } R;
#pragma unroll
    for (int j=0;j<8;j++){
      float r = fminf(gf[j], ubr) * inv;
      R.h2[j] = f2bf(sf[j] * r);
    }
    *(int4*)(stacked2 + (((b*66 + h+1)*66) + (px+1))*512 + 256 + c) = R.v;
  }
}

// new_state = s*(1-u) + o*u, NCHW fp32 out (x2 copies), via LDS transpose.
__global__ __launch_bounds__(256) void k_final(const u16* __restrict__ G,
    const u16* __restrict__ O, const float* __restrict__ in_state,
    const float* __restrict__ ubs, float* __restrict__ dout){
  __shared__ float Q[64*65];
  __shared__ float P[64*65];
  int tid = threadIdx.x, bh = blockIdx.x;
  int b = bh >> 6, h = bh & 63;
  float ubu = ubs[0], inv = ubs[2];
  int px = tid >> 2, cs = (tid & 3)*16;
  int w = tid & 63, c4 = tid >> 6;
  for (int cb = 0; cb < 4; ++cb){
#pragma unroll
    for (int tt = 0; tt < 2; ++tt){
      int cl = cs + tt*8;
      int c = cb*64 + cl;
      int4 gv = *(const int4*)(G + (bh*64 + px)*512 + c);
      int4 ov = *(const int4*)(O + (bh*64 + px)*256 + c);
      float gf[8], of[8]; unpack8(gv, gf); unpack8(ov, of);
#pragma unroll
      for (int j=0;j<8;j++){
        float u = fminf(gf[j], ubu) * inv;
        Q[px*65 + cl + j] = u;
        P[px*65 + cl + j] = of[j]*u;
      }
    }
    __syncthreads();
    for (int i = 0; i < 16; ++i){
      int cl = i*4 + c4;
      int c = cb*64 + cl;
      int gidx = (((b*256 + c)*64) + h)*64 + w;
      float s = in_state[gidx];
      float v = s*(1.f - Q[w*65 + cl]) + P[w*65 + cl];
      dout[gidx] = v;
      dout[8388608 + gidx] = v;
    }
    __syncthreads();
  }
}

// ---------------------------------------------------------------------------
extern "C" void kernel_launch(void* const* d_in, const int* in_sizes, int n_in,
                              void* d_out, int out_size, void* d_ws, size_t ws_size,
                              hipStream_t stream){
  (void)in_sizes; (void)n_in; (void)out_size; (void)ws_size;
  const float* inputs   = (const float*)d_in[0];
  const float* in_state = (const float*)d_in[1];
  const float* w_reset  = (const float*)d_in[2];
  const float* b_reset  = (const float*)d_in[3];
  const float* w_update = (const float*)d_in[4];
  const float* b_update = (const float*)d_in[5];
  const float* w_out    = (const float*)d_in[6];
  const float* b_out    = (const float*)d_in[7];
  const float* w_offset = (const float*)d_in[8];
  const float* w_align  = (const float*)d_in[9];
  float* dout = (float*)d_out;

  char* ws = (char*)d_ws;
  size_t off = 0;
  auto alloc = [&](size_t bytes)->char*{
    char* p = ws + off; off = (off + bytes + 255) & ~(size_t)255; return p;
  };
  const size_t x2pad_b   = 8ull*72*72*256*2;
  const size_t stacked_b = 8ull*66*66*512*2;
  u16* x2pad    = (u16*)alloc(x2pad_b);
  u16* stacked  = (u16*)alloc(stacked_b);
  u16* stacked2 = (u16*)alloc(stacked_b);
  float* corr   = (float*)alloc(8ull*64*64*81*4);
  float* offs   = (float*)alloc(8ull*64*64*18*4);
  u16* G        = (u16*)alloc(8ull*64*64*512*2);
  u16* O        = (u16*)alloc(8ull*64*64*256*2);
  u16* wgate    = (u16*)alloc(512ull*4608*2);
  u16* woutb    = (u16*)alloc(256ull*4608*2);
  u16* walignb  = (u16*)alloc(256ull*2304*2);
  float* woff   = (float*)alloc(1458*4);
  float* biascat= (float*)alloc(512*4);
  float* partials=(float*)alloc(1024*3*4);
  float* ubs    = (float*)alloc(4*4);

  hipMemsetAsync(x2pad,    0, x2pad_b,   stream);
  hipMemsetAsync(stacked,  0, stacked_b, stream);
  hipMemsetAsync(stacked2, 0, stacked_b, stream);

  k_repack<<<9216, 256, 0, stream>>>(w_reset, b_reset, w_update, b_update, w_out,
                                     w_offset, w_align, wgate, woutb, walignb, woff, biascat);
  k_transform<<<512, 256, 0, stream>>>(inputs, in_state, stacked, stacked2, x2pad);
  k_corr<<<512, 256, 0, stream>>>(stacked, x2pad, corr);
  k_offset<<<1024, 256, 0, stream>>>(corr, woff, offs);
  k_deform<<<512, 256, 0, stream>>>(x2pad, offs, walignb, stacked);
  k_conv128<4,true><<<1024, 256, 0, stream>>>(stacked, wgate, biascat, G, partials);
  k_finalize<<<1, 256, 0, stream>>>(partials, ubs);
  k_mulreset<<<512, 256, 0, stream>>>(G, x2pad, ubs, stacked2);
  k_conv128<2,false><<<512, 256, 0, stream>>>(stacked2, woutb, b_out, O, nullptr);
  k_final<<<512, 256, 0, stream>>>(G, O, in_state, ubs, dout);
}